// Round 13
// baseline (128.233 us; speedup 1.0000x reference)
//
#include <hip/hip_runtime.h>
#include <math.h>

#define NB 4
#define LL 4096
#define DD 1024
#define MM 256

typedef short s16x8 __attribute__((ext_vector_type(8)));
typedef short s16x4 __attribute__((ext_vector_type(4)));
typedef float fx4 __attribute__((ext_vector_type(4)));
typedef unsigned u32x2 __attribute__((ext_vector_type(2)));
typedef unsigned u32x4 __attribute__((ext_vector_type(4)));

__device__ __forceinline__ float b2f(short s) {
  union { unsigned u; float f; } v;
  v.u = ((unsigned)(unsigned short)s) << 16;
  return v.f;
}
__device__ __forceinline__ short f2b(float f) {
  union { float f; unsigned u; } v;
  v.f = f;
  unsigned r = (v.u + 0x7fffu + ((v.u >> 16) & 1u)) >> 16;
  return (short)(unsigned short)r;
}
// packed fp32->bf16 (RNE), 2 values per instruction
__device__ __forceinline__ unsigned cvt2(float lo, float hi) {
  unsigned r;
  asm("v_cvt_pk_bf16_f32 %0, %1, %2" : "=v"(r) : "v"(lo), "v"(hi));
  return r;
}
// 64-elem (128B) rows, XOR swizzle on 8-elem granule
__device__ __forceinline__ int swz(int row, int col) {
  return row * 64 + (col ^ ((row & 7) << 3));
}
// 4-chunk swizzle key for 32-k-wide bf16 tiles
__device__ __forceinline__ int keyf(int m) { return (m ^ (m >> 2)) & 3; }

typedef __attribute__((address_space(1))) const void* gas1_t;
typedef __attribute__((address_space(3))) void* las3_t;
#define GLL16(g, l) __builtin_amdgcn_global_load_lds((gas1_t)(const void*)(g), (las3_t)(void*)(l), 16, 0, 0)

// ---------------- cast fp32 -> bf16 (P only) ----------------
__global__ __launch_bounds__(256) void k_cast(const float* __restrict__ in, short* __restrict__ out, int n4) {
  int i = blockIdx.x * 256 + threadIdx.x;
  if (i >= n4) return;
  float4 v = ((const float4*)in)[i];
  s16x4 s;
  s[0] = f2b(v.x); s[1] = f2b(v.y); s[2] = f2b(v.z); s[3] = f2b(v.w);
  ((s16x4*)out)[i] = s;
}

// ---------------- rf GEMM, merged-QK: 64 Q-rows + 64 K-rows share one Pb tile ----------------
// 512 thr / 8 waves: waves 0-3 -> Q-half (rows 0-63), waves 4-7 -> K-half (rows 64-127).
// Per step: A 128x64 fp32 reg-staged (1/2 of old B traffic amortization doubled), B 256x64 bf16 GLL16.
__global__ __launch_bounds__(512, 2) void k_qk(const float* __restrict__ Q, const float* __restrict__ K,
                                               const short* __restrict__ Pb,
                                               short* __restrict__ rfq, short* __restrict__ rfkT,
                                               float* __restrict__ Zz) {
  __shared__ short As[2][8192];    // [128 rows][64 k] bf16 swz (0-63 Q, 64-127 K), 16KB x2
  __shared__ short Bs[2][16384];   // [256 m][64 k] bf16 swz, 32KB x2
  int b = blockIdx.z;
  int l0 = blockIdx.x * 64;
  int tid = threadIdx.x, lane = tid & 63, w = tid >> 6;
  int wr = w >> 2, wq = w & 3;     // wr: 0=Q-half 1=K-half; wq: m-quadrant
  int m16 = lane & 15, kg = lane >> 4;

  // A staging: arow = tid>>2 (0..127), 16 contiguous k per thread
  int arow = tid >> 2, acol = (tid & 3) * 16;
  int akey = (arow & 7) << 3;
  const float* Xr = (arow < 64 ? Q + ((size_t)b * LL + l0 + arow) * DD
                               : K + ((size_t)b * LL + l0 + arow - 64) * DD) + acol;

  fx4 acc[4][4] = {};
  float4 pa[4];

  // prologue: tile 0
  #pragma unroll
  for (int i = 0; i < 4; ++i) pa[i] = *(const float4*)(Xr + i * 4);
  #pragma unroll
  for (int j = 0; j < 4; ++j) {
    int fl = tid + j * 512, row = fl >> 3, c8 = fl & 7;
    GLL16(Pb + (size_t)row * DD + (c8 ^ (row & 7)) * 8, &Bs[0][fl * 8]);
  }
  {
    u32x4 v0;
    v0[0] = cvt2(pa[0].x, pa[0].y); v0[1] = cvt2(pa[0].z, pa[0].w);
    v0[2] = cvt2(pa[1].x, pa[1].y); v0[3] = cvt2(pa[1].z, pa[1].w);
    *(u32x4*)&As[0][arow * 64 + (acol ^ akey)] = v0;
    v0[0] = cvt2(pa[2].x, pa[2].y); v0[1] = cvt2(pa[2].z, pa[2].w);
    v0[2] = cvt2(pa[3].x, pa[3].y); v0[3] = cvt2(pa[3].z, pa[3].w);
    *(u32x4*)&As[0][arow * 64 + ((acol + 8) ^ akey)] = v0;
  }
  __syncthreads();

  for (int t = 0; t < 16; ++t) {
    int cur = t & 1, nxt = cur ^ 1;
    if (t < 15) {
      int d1 = (t + 1) * 64;
      #pragma unroll
      for (int i = 0; i < 4; ++i) pa[i] = *(const float4*)(Xr + d1 + i * 4);
      #pragma unroll
      for (int j = 0; j < 4; ++j) {
        int fl = tid + j * 512, row = fl >> 3, c8 = fl & 7;
        GLL16(Pb + (size_t)row * DD + d1 + (c8 ^ (row & 7)) * 8, &Bs[nxt][fl * 8]);
      }
    }
    #pragma unroll
    for (int ks = 0; ks < 2; ++ks) {
      int kb = ks * 32 + kg * 8;
      s16x8 af[4], bf[4];
      #pragma unroll
      for (int mi = 0; mi < 4; ++mi) af[mi] = *(const s16x8*)&As[cur][swz(wr * 64 + mi * 16 + m16, kb)];
      #pragma unroll
      for (int ni = 0; ni < 4; ++ni) bf[ni] = *(const s16x8*)&Bs[cur][swz(wq * 64 + ni * 16 + m16, kb)];
      #pragma unroll
      for (int mi = 0; mi < 4; ++mi)
        #pragma unroll
        for (int ni = 0; ni < 4; ++ni)
          acc[mi][ni] = __builtin_amdgcn_mfma_f32_16x16x32_bf16(af[mi], bf[ni], acc[mi][ni], 0, 0, 0);
    }
    if (t < 15) {
      u32x4 v0;
      v0[0] = cvt2(pa[0].x, pa[0].y); v0[1] = cvt2(pa[0].z, pa[0].w);
      v0[2] = cvt2(pa[1].x, pa[1].y); v0[3] = cvt2(pa[1].z, pa[1].w);
      *(u32x4*)&As[nxt][arow * 64 + (acol ^ akey)] = v0;
      v0[0] = cvt2(pa[2].x, pa[2].y); v0[1] = cvt2(pa[2].z, pa[2].w);
      v0[2] = cvt2(pa[3].x, pa[3].y); v0[3] = cvt2(pa[3].z, pa[3].w);
      *(u32x4*)&As[nxt][arow * 64 + ((acol + 8) ^ akey)] = v0;
    }
    __syncthreads();
  }

  if (wr == 0) {
    // Q epilogue: direct store with exp * 1/sqrt(M)
    #pragma unroll
    for (int mi = 0; mi < 4; ++mi)
      #pragma unroll
      for (int ni = 0; ni < 4; ++ni) {
        int r0 = mi * 16 + (kg << 2);
        int c = wq * 64 + ni * 16 + m16;
        #pragma unroll
        for (int u = 0; u < 4; ++u)
          rfq[((size_t)b * LL + l0 + r0 + u) * MM + c] = f2b(expf(acc[mi][ni][u] * 0.03125f) * 0.0625f);
      }
  } else {
    // K epilogue: bounce C^T into Bs overlay [256 m][64 l] (32 KB), fused Z partials
    short* T = (short*)Bs;
    float zp[4] = {0.f, 0.f, 0.f, 0.f};
    #pragma unroll
    for (int mi = 0; mi < 4; ++mi)
      #pragma unroll
      for (int ni = 0; ni < 4; ++ni) {
        int l = mi * 16 + (kg << 2);
        int m = wq * 64 + ni * 16 + m16;
        int key = (m & 7) << 3;
        float e0 = expf(acc[mi][ni][0] * 0.03125f);
        float e1 = expf(acc[mi][ni][1] * 0.03125f);
        float e2 = expf(acc[mi][ni][2] * 0.03125f);
        float e3 = expf(acc[mi][ni][3] * 0.03125f);
        zp[ni] += e0 + e1 + e2 + e3;
        *(unsigned*)&T[m * 64 + (l ^ key)] = cvt2(e0, e1);
        *(unsigned*)&T[m * 64 + ((l ^ key) + 2)] = cvt2(e2, e3);
      }
    #pragma unroll
    for (int ni = 0; ni < 4; ++ni) {
      zp[ni] += __shfl_xor(zp[ni], 16);
      zp[ni] += __shfl_xor(zp[ni], 32);
    }
    if (kg == 0) {
      #pragma unroll
      for (int ni = 0; ni < 4; ++ni)
        atomicAdd(&Zz[b * MM + wq * 64 + ni * 16 + m16], zp[ni]);
    }
  }
  __syncthreads();
  if (tid >= 256) {
    int m = tid - 256, mkey = (m & 7) << 3;
    const short* T = (const short*)Bs;
    short* dst = rfkT + ((size_t)b * MM + m) * LL + l0;
    #pragma unroll
    for (int j = 0; j < 8; ++j) {
      s16x8 v = *(const s16x8*)&T[m * 64 + ((j * 8) ^ mkey)];
      *(s16x8*)(dst + j * 8) = v;
    }
  }
}

// ---------------- KV partials: KVp[kc][b][d][m], d-tile 64 -> 512 blocks, 16 waves/CU ----------------
__global__ __launch_bounds__(512, 4) void k_kv(const float* __restrict__ V, const short* __restrict__ rfkT,
                                               float* __restrict__ KVp) {
  __shared__ float Vs[2][32 * 65];    // fp32 [32 l][65 d-pitch], 8.3 KB x2
  __shared__ short Ak[2][256 * 32];   // rfkT [256 m][32 l] bf16, keyf swz, 16 KB x2
  int d0 = blockIdx.x * 64, kc = blockIdx.y, b = blockIdx.z;
  int ls = kc * 512;
  int tid = threadIdx.x, lane = tid & 63, w = tid >> 6;
  int wm = w >> 1, wd = w & 1;     // 4(m) x 2(d)
  int m16 = lane & 15, kg = lane >> 4;

  int vl = tid >> 4, vf = (tid & 15) * 4;
  const float* Vb = V + ((size_t)b * LL + ls + vl) * DD + d0 + vf;

  int am = tid >> 2, as = tid & 3;
  const short* AkS0 = rfkT + ((size_t)b * MM + am) * LL + ls + (as ^ keyf(am)) * 8;
  const short* AkS1 = rfkT + ((size_t)b * MM + am + 128) * LL + ls + (as ^ keyf(am + 128)) * 8;

  fx4 acc[4][2] = {};
  float4 pv;

  pv = *(const float4*)(Vb);
  GLL16(AkS0, &Ak[0][tid * 8]);
  GLL16(AkS1, &Ak[0][(tid + 512) * 8]);
  #pragma unroll
  for (int j = 0; j < 4; ++j) Vs[0][vl * 65 + vf + j] = ((const float*)&pv)[j];
  __syncthreads();

  for (int ch = 0; ch < 16; ++ch) {
    int cur = ch & 1, nxt = cur ^ 1;
    if (ch < 15) {
      int lo = (ch + 1) * 32;
      pv = *(const float4*)(Vb + (size_t)lo * DD);
      GLL16(AkS0 + lo, &Ak[nxt][tid * 8]);
      GLL16(AkS1 + lo, &Ak[nxt][(tid + 512) * 8]);
    }
    s16x8 af[4];
    #pragma unroll
    for (int mi = 0; mi < 4; ++mi) {
      int m = wm * 64 + mi * 16 + m16;
      af[mi] = *(const s16x8*)&Ak[cur][m * 32 + ((kg ^ keyf(m)) * 8)];
    }
    #pragma unroll
    for (int ni = 0; ni < 2; ++ni) {
      int d = wd * 32 + ni * 16 + m16;
      const float* vs = &Vs[cur][kg * 8 * 65 + d];
      u32x4 bw;
      bw[0] = cvt2(vs[0], vs[65]);
      bw[1] = cvt2(vs[130], vs[195]);
      bw[2] = cvt2(vs[260], vs[325]);
      bw[3] = cvt2(vs[390], vs[455]);
      s16x8 bf = *(s16x8*)&bw;
      #pragma unroll
      for (int mi = 0; mi < 4; ++mi)
        acc[mi][ni] = __builtin_amdgcn_mfma_f32_16x16x32_bf16(af[mi], bf, acc[mi][ni], 0, 0, 0);
    }
    if (ch < 15) {
      #pragma unroll
      for (int j = 0; j < 4; ++j) Vs[nxt][vl * 65 + vf + j] = ((const float*)&pv)[j];
    }
    __syncthreads();
  }

  float* dst = KVp + (((size_t)kc * NB + b) * DD + d0) * MM;
  #pragma unroll
  for (int mi = 0; mi < 4; ++mi)
    #pragma unroll
    for (int ni = 0; ni < 2; ++ni) {
      int d = wd * 32 + ni * 16 + m16;
      int m = wm * 64 + mi * 16 + (kg << 2);
      *(float4*)(dst + (size_t)d * MM + m) = *(float4*)&acc[mi][ni];
    }
}

// ---------------- reduce 8 split-K partials -> KVT bf16 ----------------
__global__ __launch_bounds__(256) void k_red(const float* __restrict__ KVp, short* __restrict__ KVTb) {
  int i = blockIdx.x * 256 + threadIdx.x;
  const float4* p = (const float4*)KVp;
  float4 s = p[i];
  #pragma unroll
  for (int k = 1; k < 8; ++k) {
    float4 v = p[i + k * 262144];
    s.x += v.x; s.y += v.y; s.z += v.z; s.w += v.w;
  }
  u32x2 o;
  o[0] = cvt2(s.x, s.y);
  o[1] = cvt2(s.z, s.w);
  ((u32x2*)KVTb)[i] = o;
}

// ---------------- out = (rf_q x KVT^T) / (rf_q . Z + eps); KVT bf16 via GLL16 ----------------
__global__ __launch_bounds__(512) void k_out(const short* __restrict__ rfq, const short* __restrict__ KVTb,
                                             const float* __restrict__ Zz, float* __restrict__ out) {
  __shared__ short Aq[2][8192];   // [128 l][64 m]
  __shared__ short Bv[2][8192];   // [128 d][64 m]
  __shared__ float zl[256];
  __shared__ float np[512];
  __shared__ float nf[128];
  int l0 = blockIdx.x * 128, d0 = blockIdx.y * 128, b = blockIdx.z;
  int tid = threadIdx.x, lane = tid & 63, w = tid >> 6;
  int wr = w >> 2, wc = w & 3;               // 2(l) x 4(d)
  const short* Ab = rfq + ((size_t)b * LL + l0) * MM;
  const short* Bb = KVTb + ((size_t)b * DD + d0) * MM;
  int f1 = tid + 512;
  int ar0 = tid >> 3, ac0 = tid & 7, ar1 = f1 >> 3, ac1 = f1 & 7;
  int nrow = tid & 127, nsub = tid >> 7;
  if (tid < 256) zl[tid] = Zz[b * MM + tid];
  fx4 acc[4][2] = {};
  float na = 0.f;

  GLL16(Ab + (size_t)ar0 * MM + (ac0 ^ (ar0 & 7)) * 8, &Aq[0][tid * 8]);
  GLL16(Ab + (size_t)ar1 * MM + (ac1 ^ (ar1 & 7)) * 8, &Aq[0][f1 * 8]);
  GLL16(Bb + (size_t)ar0 * MM + (ac0 ^ (ar0 & 7)) * 8, &Bv[0][tid * 8]);
  GLL16(Bb + (size_t)ar1 * MM + (ac1 ^ (ar1 & 7)) * 8, &Bv[0][f1 * 8]);
  __syncthreads();

  for (int t = 0; t < 4; ++t) {
    int cur = t & 1, nxt = cur ^ 1;
    if (t < 3) {
      int m1 = (t + 1) * 64;
      GLL16(Ab + (size_t)ar0 * MM + m1 + (ac0 ^ (ar0 & 7)) * 8, &Aq[nxt][tid * 8]);
      GLL16(Ab + (size_t)ar1 * MM + m1 + (ac1 ^ (ar1 & 7)) * 8, &Aq[nxt][f1 * 8]);
      GLL16(Bb + (size_t)ar0 * MM + m1 + (ac0 ^ (ar0 & 7)) * 8, &Bv[nxt][tid * 8]);
      GLL16(Bb + (size_t)ar1 * MM + m1 + (ac1 ^ (ar1 & 7)) * 8, &Bv[nxt][f1 * 8]);
    }
    // normalizer partial: 4 threads per row, 16 k each
    #pragma unroll
    for (int kk = 0; kk < 16; ++kk) {
      int k = nsub * 16 + kk;
      na += b2f(Aq[cur][nrow * 64 + (k ^ ((nrow & 7) << 3))]) * zl[t * 64 + k];
    }
    #pragma unroll
    for (int ks = 0; ks < 2; ++ks) {
      int kb = ks * 32 + (lane >> 4) * 8;
      s16x8 af[4], bf[2];
      #pragma unroll
      for (int mi = 0; mi < 4; ++mi) {
        int row = wr * 64 + mi * 16 + (lane & 15);
        af[mi] = *(const s16x8*)&Aq[cur][row * 64 + (kb ^ ((row & 7) << 3))];
      }
      #pragma unroll
      for (int ni = 0; ni < 2; ++ni) {
        int row = wc * 32 + ni * 16 + (lane & 15);
        bf[ni] = *(const s16x8*)&Bv[cur][row * 64 + (kb ^ ((row & 7) << 3))];
      }
      #pragma unroll
      for (int mi = 0; mi < 4; ++mi)
        #pragma unroll
        for (int ni = 0; ni < 2; ++ni)
          acc[mi][ni] = __builtin_amdgcn_mfma_f32_16x16x32_bf16(af[mi], bf[ni], acc[mi][ni], 0, 0, 0);
    }
    __syncthreads();
  }
  np[tid] = na;
  __syncthreads();
  if (tid < 128) nf[tid] = np[tid] + np[tid + 128] + np[tid + 256] + np[tid + 384] + 1e-6f;
  __syncthreads();
  #pragma unroll
  for (int mi = 0; mi < 4; ++mi)
    #pragma unroll
    for (int ni = 0; ni < 2; ++ni) {
      int l = wr * 64 + mi * 16 + ((lane >> 4) << 2);
      int d = d0 + wc * 32 + ni * 16 + (lane & 15);
      #pragma unroll
      for (int u = 0; u < 4; ++u)
        out[((size_t)b * LL + l0 + l + u) * DD + d] = acc[mi][ni][u] / nf[l + u];
    }
}

extern "C" void kernel_launch(void* const* d_in, const int* in_sizes, int n_in,
                              void* d_out, int out_size, void* d_ws, size_t ws_size,
                              hipStream_t stream) {
  const float* Q = (const float*)d_in[0];
  const float* K = (const float*)d_in[1];
  const float* V = (const float*)d_in[2];
  const float* P = (const float*)d_in[3];
  float* out = (float*)d_out;
  char* ws = (char*)d_ws;

  short* Pb   = (short*)(ws + 0);          // 256*1024*2    = 512 KB
  float* Zz   = (float*)(ws + 524288);     // 4*256*4       = 4 KB
  short* KVTb = (short*)(ws + 528384);     // 4*1024*256*2  = 2 MB
  short* rfq  = (short*)(ws + 4722688);    // 4*4096*256*2  = 8 MB
  short* rfkT = (short*)(ws + 13111296);   // 4*256*4096*2  = 8 MB
  float* KVp  = (float*)(ws + 21499904);   // 8*4*1024*256*4 = 32 MB

  k_cast<<<256, 256, 0, stream>>>(P, Pb, 65536);
  (void)hipMemsetAsync(Zz, 0, 4096, stream);
  k_qk<<<dim3(64, 1, NB), 512, 0, stream>>>(Q, K, Pb, rfq, rfkT, Zz);
  k_kv<<<dim3(16, 8, NB), 512, 0, stream>>>(V, rfkT, KVp);
  k_red<<<1024, 256, 0, stream>>>(KVp, KVTb);
  k_out<<<dim3(32, 8, NB), 512, 0, stream>>>(rfq, KVTb, Zz, out);
}

// Round 14
// 124.836 us; speedup vs baseline: 1.0272x; 1.0272x over previous
//
#include <hip/hip_runtime.h>
#include <math.h>

#define NB 4
#define LL 4096
#define DD 1024
#define MM 256

typedef short s16x8 __attribute__((ext_vector_type(8)));
typedef short s16x4 __attribute__((ext_vector_type(4)));
typedef float fx4 __attribute__((ext_vector_type(4)));
typedef unsigned u32x2 __attribute__((ext_vector_type(2)));
typedef unsigned u32x4 __attribute__((ext_vector_type(4)));

__device__ __forceinline__ float b2f(short s) {
  union { unsigned u; float f; } v;
  v.u = ((unsigned)(unsigned short)s) << 16;
  return v.f;
}
__device__ __forceinline__ short f2b(float f) {
  union { float f; unsigned u; } v;
  v.f = f;
  unsigned r = (v.u + 0x7fffu + ((v.u >> 16) & 1u)) >> 16;
  return (short)(unsigned short)r;
}
// packed fp32->bf16 (RNE), 2 values per instruction
__device__ __forceinline__ unsigned cvt2(float lo, float hi) {
  unsigned r;
  asm("v_cvt_pk_bf16_f32 %0, %1, %2" : "=v"(r) : "v"(lo), "v"(hi));
  return r;
}
// 64-elem (128B) rows, XOR swizzle on 8-elem granule
__device__ __forceinline__ int swz(int row, int col) {
  return row * 64 + (col ^ ((row & 7) << 3));
}
// 4-chunk swizzle key for 32-k-wide bf16 tiles
__device__ __forceinline__ int keyf(int m) { return (m ^ (m >> 2)) & 3; }

typedef __attribute__((address_space(1))) const void* gas1_t;
typedef __attribute__((address_space(3))) void* las3_t;
#define GLL16(g, l) __builtin_amdgcn_global_load_lds((gas1_t)(const void*)(g), (las3_t)(void*)(l), 16, 0, 0)

// ---------------- cast fp32 -> bf16 (P only) ----------------
__global__ __launch_bounds__(256) void k_cast(const float* __restrict__ in, short* __restrict__ out, int n4) {
  int i = blockIdx.x * 256 + threadIdx.x;
  if (i >= n4) return;
  float4 v = ((const float4*)in)[i];
  s16x4 s;
  s[0] = f2b(v.x); s[1] = f2b(v.y); s[2] = f2b(v.z); s[3] = f2b(v.w);
  ((s16x4*)out)[i] = s;
}

// ---------------- rf GEMM, merged-QK + per-block K-phase rotation ----------------
// 512 thr / 8 waves: waves 0-3 -> Q-half (rows 0-63), waves 4-7 -> K-half (rows 64-127).
// Each block walks K-chunks starting at phase (decorrelates addr bits 8-11 chip-wide).
__global__ __launch_bounds__(512, 2) void k_qk(const float* __restrict__ Q, const float* __restrict__ K,
                                               const short* __restrict__ Pb,
                                               short* __restrict__ rfq, short* __restrict__ rfkT,
                                               float* __restrict__ Zz) {
  __shared__ short As[2][8192];    // [128 rows][64 k] bf16 swz (0-63 Q, 64-127 K), 16KB x2
  __shared__ short Bs[2][16384];   // [256 m][64 k] bf16 swz, 32KB x2
  int b = blockIdx.z;
  int l0 = blockIdx.x * 64;
  int phase = (blockIdx.x + blockIdx.z * 4) & 15;
  int tid = threadIdx.x, lane = tid & 63, w = tid >> 6;
  int wr = w >> 2, wq = w & 3;     // wr: 0=Q-half 1=K-half; wq: m-quadrant
  int m16 = lane & 15, kg = lane >> 4;

  // A staging: arow = tid>>2 (0..127), 16 contiguous k per thread
  int arow = tid >> 2, acol = (tid & 3) * 16;
  int akey = (arow & 7) << 3;
  const float* Xr = (arow < 64 ? Q + ((size_t)b * LL + l0 + arow) * DD
                               : K + ((size_t)b * LL + l0 + arow - 64) * DD) + acol;

  fx4 acc[4][4] = {};
  float4 pa[4];

  // prologue: rotated chunk 0
  {
    int d0 = phase * 64;
    #pragma unroll
    for (int i = 0; i < 4; ++i) pa[i] = *(const float4*)(Xr + d0 + i * 4);
    #pragma unroll
    for (int j = 0; j < 4; ++j) {
      int fl = tid + j * 512, row = fl >> 3, c8 = fl & 7;
      GLL16(Pb + (size_t)row * DD + d0 + (c8 ^ (row & 7)) * 8, &Bs[0][fl * 8]);
    }
    u32x4 v0;
    v0[0] = cvt2(pa[0].x, pa[0].y); v0[1] = cvt2(pa[0].z, pa[0].w);
    v0[2] = cvt2(pa[1].x, pa[1].y); v0[3] = cvt2(pa[1].z, pa[1].w);
    *(u32x4*)&As[0][arow * 64 + (acol ^ akey)] = v0;
    v0[0] = cvt2(pa[2].x, pa[2].y); v0[1] = cvt2(pa[2].z, pa[2].w);
    v0[2] = cvt2(pa[3].x, pa[3].y); v0[3] = cvt2(pa[3].z, pa[3].w);
    *(u32x4*)&As[0][arow * 64 + ((acol + 8) ^ akey)] = v0;
  }
  __syncthreads();

  for (int t = 0; t < 16; ++t) {
    int cur = t & 1, nxt = cur ^ 1;
    if (t < 15) {
      int d1 = (((t + 1) + phase) & 15) * 64;
      #pragma unroll
      for (int i = 0; i < 4; ++i) pa[i] = *(const float4*)(Xr + d1 + i * 4);
      #pragma unroll
      for (int j = 0; j < 4; ++j) {
        int fl = tid + j * 512, row = fl >> 3, c8 = fl & 7;
        GLL16(Pb + (size_t)row * DD + d1 + (c8 ^ (row & 7)) * 8, &Bs[nxt][fl * 8]);
      }
    }
    #pragma unroll
    for (int ks = 0; ks < 2; ++ks) {
      int kb = ks * 32 + kg * 8;
      s16x8 af[4], bf[4];
      #pragma unroll
      for (int mi = 0; mi < 4; ++mi) af[mi] = *(const s16x8*)&As[cur][swz(wr * 64 + mi * 16 + m16, kb)];
      #pragma unroll
      for (int ni = 0; ni < 4; ++ni) bf[ni] = *(const s16x8*)&Bs[cur][swz(wq * 64 + ni * 16 + m16, kb)];
      #pragma unroll
      for (int mi = 0; mi < 4; ++mi)
        #pragma unroll
        for (int ni = 0; ni < 4; ++ni)
          acc[mi][ni] = __builtin_amdgcn_mfma_f32_16x16x32_bf16(af[mi], bf[ni], acc[mi][ni], 0, 0, 0);
    }
    if (t < 15) {
      u32x4 v0;
      v0[0] = cvt2(pa[0].x, pa[0].y); v0[1] = cvt2(pa[0].z, pa[0].w);
      v0[2] = cvt2(pa[1].x, pa[1].y); v0[3] = cvt2(pa[1].z, pa[1].w);
      *(u32x4*)&As[nxt][arow * 64 + (acol ^ akey)] = v0;
      v0[0] = cvt2(pa[2].x, pa[2].y); v0[1] = cvt2(pa[2].z, pa[2].w);
      v0[2] = cvt2(pa[3].x, pa[3].y); v0[3] = cvt2(pa[3].z, pa[3].w);
      *(u32x4*)&As[nxt][arow * 64 + ((acol + 8) ^ akey)] = v0;
    }
    __syncthreads();
  }

  if (wr == 0) {
    // Q epilogue: direct store with exp * 1/sqrt(M)
    #pragma unroll
    for (int mi = 0; mi < 4; ++mi)
      #pragma unroll
      for (int ni = 0; ni < 4; ++ni) {
        int r0 = mi * 16 + (kg << 2);
        int c = wq * 64 + ni * 16 + m16;
        #pragma unroll
        for (int u = 0; u < 4; ++u)
          rfq[((size_t)b * LL + l0 + r0 + u) * MM + c] = f2b(expf(acc[mi][ni][u] * 0.03125f) * 0.0625f);
      }
  } else {
    // K epilogue: bounce C^T into Bs overlay [256 m][64 l] (32 KB), fused Z partials
    short* T = (short*)Bs;
    float zp[4] = {0.f, 0.f, 0.f, 0.f};
    #pragma unroll
    for (int mi = 0; mi < 4; ++mi)
      #pragma unroll
      for (int ni = 0; ni < 4; ++ni) {
        int l = mi * 16 + (kg << 2);
        int m = wq * 64 + ni * 16 + m16;
        int key = (m & 7) << 3;
        float e0 = expf(acc[mi][ni][0] * 0.03125f);
        float e1 = expf(acc[mi][ni][1] * 0.03125f);
        float e2 = expf(acc[mi][ni][2] * 0.03125f);
        float e3 = expf(acc[mi][ni][3] * 0.03125f);
        zp[ni] += e0 + e1 + e2 + e3;
        *(unsigned*)&T[m * 64 + (l ^ key)] = cvt2(e0, e1);
        *(unsigned*)&T[m * 64 + ((l ^ key) + 2)] = cvt2(e2, e3);
      }
    #pragma unroll
    for (int ni = 0; ni < 4; ++ni) {
      zp[ni] += __shfl_xor(zp[ni], 16);
      zp[ni] += __shfl_xor(zp[ni], 32);
    }
    if (kg == 0) {
      #pragma unroll
      for (int ni = 0; ni < 4; ++ni)
        atomicAdd(&Zz[b * MM + wq * 64 + ni * 16 + m16], zp[ni]);
    }
  }
  __syncthreads();
  if (tid >= 256) {
    int m = tid - 256, mkey = (m & 7) << 3;
    const short* T = (const short*)Bs;
    short* dst = rfkT + ((size_t)b * MM + m) * LL + l0;
    #pragma unroll
    for (int j = 0; j < 8; ++j) {
      s16x8 v = *(const s16x8*)&T[m * 64 + ((j * 8) ^ mkey)];
      *(s16x8*)(dst + j * 8) = v;
    }
  }
}

// ---------------- KV partials (r10 proven d128): KVp[kc][b][d][m] ----------------
__global__ __launch_bounds__(512) void k_kv(const float* __restrict__ V, const short* __restrict__ rfkT,
                                            float* __restrict__ KVp) {
  __shared__ float Vs[2][32 * 129];   // fp32 [32 l][129 d-pitch] (odd pitch: conflict-free col reads)
  __shared__ short Ak[2][256 * 32];   // rfkT [256 m][32 l] bf16, 4-chunk swizzled
  int d0 = blockIdx.x * 128, kc = blockIdx.y, b = blockIdx.z;
  int ls = kc * 512;
  int tid = threadIdx.x, lane = tid & 63, w = tid >> 6;
  int wm = w >> 1, wd = w & 1;     // 4(m) x 2(d)
  int m16 = lane & 15, kg = lane >> 4;

  int vl = tid >> 4, vf = (tid & 15) * 8;
  const float* Vb = V + ((size_t)b * LL + ls + vl) * DD + d0 + vf;

  int am = tid >> 2, as = tid & 3;
  int acs = as ^ keyf(am);
  const short* AkS0 = rfkT + ((size_t)b * MM + am) * LL + ls + acs * 8;
  const short* AkS1 = rfkT + ((size_t)b * MM + am + 128) * LL + ls + acs * 8;

  fx4 acc[4][4] = {};
  float4 pv0, pv1;

  pv0 = *(const float4*)(Vb);
  pv1 = *(const float4*)(Vb + 4);
  GLL16(AkS0, &Ak[0][tid * 8]);
  GLL16(AkS1, &Ak[0][(tid + 512) * 8]);
  #pragma unroll
  for (int j = 0; j < 4; ++j) {
    Vs[0][vl * 129 + vf + j] = ((const float*)&pv0)[j];
    Vs[0][vl * 129 + vf + 4 + j] = ((const float*)&pv1)[j];
  }
  __syncthreads();

  for (int ch = 0; ch < 16; ++ch) {
    int cur = ch & 1, nxt = cur ^ 1;
    if (ch < 15) {
      int lo = (ch + 1) * 32;
      pv0 = *(const float4*)(Vb + (size_t)lo * DD);
      pv1 = *(const float4*)(Vb + (size_t)lo * DD + 4);
      GLL16(AkS0 + lo, &Ak[nxt][tid * 8]);
      GLL16(AkS1 + lo, &Ak[nxt][(tid + 512) * 8]);
    }
    s16x8 af[4];
    #pragma unroll
    for (int mi = 0; mi < 4; ++mi) {
      int m = wm * 64 + mi * 16 + m16;
      af[mi] = *(const s16x8*)&Ak[cur][m * 32 + ((kg ^ keyf(m)) * 8)];
    }
    #pragma unroll
    for (int ni = 0; ni < 4; ++ni) {
      int d = wd * 64 + ni * 16 + m16;
      const float* vs = &Vs[cur][kg * 8 * 129 + d];
      u32x4 bw;
      bw[0] = cvt2(vs[0], vs[129]);
      bw[1] = cvt2(vs[258], vs[387]);
      bw[2] = cvt2(vs[516], vs[645]);
      bw[3] = cvt2(vs[774], vs[903]);
      s16x8 bf = *(s16x8*)&bw;
      #pragma unroll
      for (int mi = 0; mi < 4; ++mi)
        acc[mi][ni] = __builtin_amdgcn_mfma_f32_16x16x32_bf16(af[mi], bf, acc[mi][ni], 0, 0, 0);
    }
    if (ch < 15) {
      #pragma unroll
      for (int j = 0; j < 4; ++j) {
        Vs[nxt][vl * 129 + vf + j] = ((const float*)&pv0)[j];
        Vs[nxt][vl * 129 + vf + 4 + j] = ((const float*)&pv1)[j];
      }
    }
    __syncthreads();
  }

  float* dst = KVp + (((size_t)kc * NB + b) * DD + d0) * MM;
  #pragma unroll
  for (int mi = 0; mi < 4; ++mi)
    #pragma unroll
    for (int ni = 0; ni < 4; ++ni) {
      int d = wd * 64 + ni * 16 + m16;
      int m = wm * 64 + mi * 16 + (kg << 2);
      *(float4*)(dst + (size_t)d * MM + m) = *(float4*)&acc[mi][ni];
    }
}

// ---------------- reduce 8 split-K partials -> KVT bf16 ----------------
__global__ __launch_bounds__(256) void k_red(const float* __restrict__ KVp, short* __restrict__ KVTb) {
  int i = blockIdx.x * 256 + threadIdx.x;
  const float4* p = (const float4*)KVp;
  float4 s = p[i];
  #pragma unroll
  for (int k = 1; k < 8; ++k) {
    float4 v = p[i + k * 262144];
    s.x += v.x; s.y += v.y; s.z += v.z; s.w += v.w;
  }
  u32x2 o;
  o[0] = cvt2(s.x, s.y);
  o[1] = cvt2(s.z, s.w);
  ((u32x2*)KVTb)[i] = o;
}

// ---------------- out = (rf_q x KVT^T) / (rf_q . Z + eps); KVT bf16 via GLL16 ----------------
__global__ __launch_bounds__(512) void k_out(const short* __restrict__ rfq, const short* __restrict__ KVTb,
                                             const float* __restrict__ Zz, float* __restrict__ out) {
  __shared__ short Aq[2][8192];   // [128 l][64 m]
  __shared__ short Bv[2][8192];   // [128 d][64 m]
  __shared__ float zl[256];
  __shared__ float np[512];
  __shared__ float nf[128];
  int l0 = blockIdx.x * 128, d0 = blockIdx.y * 128, b = blockIdx.z;
  int tid = threadIdx.x, lane = tid & 63, w = tid >> 6;
  int wr = w >> 2, wc = w & 3;               // 2(l) x 4(d)
  const short* Ab = rfq + ((size_t)b * LL + l0) * MM;
  const short* Bb = KVTb + ((size_t)b * DD + d0) * MM;
  int f1 = tid + 512;
  int ar0 = tid >> 3, ac0 = tid & 7, ar1 = f1 >> 3, ac1 = f1 & 7;
  int nrow = tid & 127, nsub = tid >> 7;
  if (tid < 256) zl[tid] = Zz[b * MM + tid];
  fx4 acc[4][2] = {};
  float na = 0.f;

  GLL16(Ab + (size_t)ar0 * MM + (ac0 ^ (ar0 & 7)) * 8, &Aq[0][tid * 8]);
  GLL16(Ab + (size_t)ar1 * MM + (ac1 ^ (ar1 & 7)) * 8, &Aq[0][f1 * 8]);
  GLL16(Bb + (size_t)ar0 * MM + (ac0 ^ (ar0 & 7)) * 8, &Bv[0][tid * 8]);
  GLL16(Bb + (size_t)ar1 * MM + (ac1 ^ (ar1 & 7)) * 8, &Bv[0][f1 * 8]);
  __syncthreads();

  for (int t = 0; t < 4; ++t) {
    int cur = t & 1, nxt = cur ^ 1;
    if (t < 3) {
      int m1 = (t + 1) * 64;
      GLL16(Ab + (size_t)ar0 * MM + m1 + (ac0 ^ (ar0 & 7)) * 8, &Aq[nxt][tid * 8]);
      GLL16(Ab + (size_t)ar1 * MM + m1 + (ac1 ^ (ar1 & 7)) * 8, &Aq[nxt][f1 * 8]);
      GLL16(Bb + (size_t)ar0 * MM + m1 + (ac0 ^ (ar0 & 7)) * 8, &Bv[nxt][tid * 8]);
      GLL16(Bb + (size_t)ar1 * MM + m1 + (ac1 ^ (ar1 & 7)) * 8, &Bv[nxt][f1 * 8]);
    }
    // normalizer partial: 4 threads per row, 16 k each
    #pragma unroll
    for (int kk = 0; kk < 16; ++kk) {
      int k = nsub * 16 + kk;
      na += b2f(Aq[cur][nrow * 64 + (k ^ ((nrow & 7) << 3))]) * zl[t * 64 + k];
    }
    #pragma unroll
    for (int ks = 0; ks < 2; ++ks) {
      int kb = ks * 32 + (lane >> 4) * 8;
      s16x8 af[4], bf[2];
      #pragma unroll
      for (int mi = 0; mi < 4; ++mi) {
        int row = wr * 64 + mi * 16 + (lane & 15);
        af[mi] = *(const s16x8*)&Aq[cur][row * 64 + (kb ^ ((row & 7) << 3))];
      }
      #pragma unroll
      for (int ni = 0; ni < 2; ++ni) {
        int row = wc * 32 + ni * 16 + (lane & 15);
        bf[ni] = *(const s16x8*)&Bv[cur][row * 64 + (kb ^ ((row & 7) << 3))];
      }
      #pragma unroll
      for (int mi = 0; mi < 4; ++mi)
        #pragma unroll
        for (int ni = 0; ni < 2; ++ni)
          acc[mi][ni] = __builtin_amdgcn_mfma_f32_16x16x32_bf16(af[mi], bf[ni], acc[mi][ni], 0, 0, 0);
    }
    __syncthreads();
  }
  np[tid] = na;
  __syncthreads();
  if (tid < 128) nf[tid] = np[tid] + np[tid + 128] + np[tid + 256] + np[tid + 384] + 1e-6f;
  __syncthreads();
  #pragma unroll
  for (int mi = 0; mi < 4; ++mi)
    #pragma unroll
    for (int ni = 0; ni < 2; ++ni) {
      int l = wr * 64 + mi * 16 + ((lane >> 4) << 2);
      int d = d0 + wc * 32 + ni * 16 + (lane & 15);
      #pragma unroll
      for (int u = 0; u < 4; ++u)
        out[((size_t)b * LL + l0 + l + u) * DD + d] = acc[mi][ni][u] / nf[l + u];
    }
}

extern "C" void kernel_launch(void* const* d_in, const int* in_sizes, int n_in,
                              void* d_out, int out_size, void* d_ws, size_t ws_size,
                              hipStream_t stream) {
  const float* Q = (const float*)d_in[0];
  const float* K = (const float*)d_in[1];
  const float* V = (const float*)d_in[2];
  const float* P = (const float*)d_in[3];
  float* out = (float*)d_out;
  char* ws = (char*)d_ws;

  short* Pb   = (short*)(ws + 0);          // 256*1024*2    = 512 KB
  float* Zz   = (float*)(ws + 524288);     // 4*256*4       = 4 KB
  short* KVTb = (short*)(ws + 528384);     // 4*1024*256*2  = 2 MB
  short* rfq  = (short*)(ws + 4722688);    // 4*4096*256*2  = 8 MB
  short* rfkT = (short*)(ws + 13111296);   // 4*256*4096*2  = 8 MB
  float* KVp  = (float*)(ws + 21499904);   // 8*4*1024*256*4 = 32 MB

  k_cast<<<256, 256, 0, stream>>>(P, Pb, 65536);
  (void)hipMemsetAsync(Zz, 0, 4096, stream);
  k_qk<<<dim3(64, 1, NB), 512, 0, stream>>>(Q, K, Pb, rfq, rfkT, Zz);
  k_kv<<<dim3(8, 8, NB), 512, 0, stream>>>(V, rfkT, KVp);
  k_red<<<1024, 256, 0, stream>>>(KVp, KVTb);
  k_out<<<dim3(32, 8, NB), 512, 0, stream>>>(rfq, KVTb, Zz, out);
}